// Round 4
// baseline (239.850 us; speedup 1.0000x reference)
//
#include <hip/hip_runtime.h>

typedef __bf16 bf16;
typedef __bf16 bf16x8 __attribute__((ext_vector_type(8)));
typedef float  f32x4  __attribute__((ext_vector_type(4)));

#define MFMA(a, b, c) __builtin_amdgcn_mfma_f32_16x16x32_bf16((a), (b), (c), 0, 0, 0)

static constexpr int B_   = 2;
static constexpr int T_   = 2048;
static constexpr int D_   = 1024;
static constexpr int NH_  = 16;
static constexpr int HD_  = 64;
static constexpr int WIN_ = 256;

// ---------------------------------------------------------------------------
// Input-dtype probe (kept for robustness; round-3 evidence says fp32).
// flag = 1 => inputs are fp32.
// ---------------------------------------------------------------------------
__global__ void detect_f32(const unsigned int* __restrict__ wq, int* flag) {
  const int tid = threadIdx.x;  // 64 threads
  const unsigned int wd = wq[tid];
  const unsigned int e = (wd >> 7) & 0xFF;  // bf16 exponent of low half
  int outlier = (e < 90 || e > 140) ? 1 : 0;
#pragma unroll
  for (int off = 1; off < 64; off <<= 1) outlier += __shfl_xor(outlier, off);
  if (tid == 0) *flag = (outlier > 16) ? 1 : 0;
}

__global__ __launch_bounds__(256) void conv_to_bf16(
    const void* __restrict__ src, bf16* __restrict__ dst, int n,
    const int* __restrict__ flag) {
  const int i = (blockIdx.x * 256 + threadIdx.x) * 4;
  if (i >= n) return;
  if (*flag) {
    const float4 v = *(const float4*)((const float*)src + i);
    bf16 o[4] = {(bf16)v.x, (bf16)v.y, (bf16)v.z, (bf16)v.w};
    *(uint2*)(dst + i) = *(const uint2*)o;
  } else {
    *(uint2*)(dst + i) = *(const uint2*)((const bf16*)src + i);
  }
}

// ---------------------------------------------------------------------------
// GEMM: C[M,N] = A[M,K] @ B[N,K]^T (+ bias[N]), bf16 in, fp32 acc.
// OutT = bf16 for intermediates, float for the final output buffer.
// 64x64 tile, BK=64, 256 threads = 4 waves (m92-verified structure).
//   A/B frag: row = lane&15, k = (lane>>4)*8 + j
//   C/D:      col = lane&15, row = (lane>>4)*4 + reg   (m89-verified)
// ---------------------------------------------------------------------------
template <typename OutT>
__global__ __launch_bounds__(256) void gemm_bt64(
    const bf16* __restrict__ A, const bf16* __restrict__ Bm,
    OutT* __restrict__ C, const bf16* __restrict__ bias,
    int M, int N, int K) {
  __shared__ __align__(16) bf16 As[64 * 64];
  __shared__ __align__(16) bf16 Bs[64 * 64];

  const int tid  = threadIdx.x;
  const int w    = tid >> 6;
  const int lane = tid & 63;
  const int quad = lane >> 4;
  const int l16  = lane & 15;
  const int wm   = w & 1;
  const int wn   = w >> 1;
  const int m0 = blockIdx.x * 64;
  const int n0 = blockIdx.y * 64;

  f32x4 acc[2][2] = {};

  for (int k0 = 0; k0 < K; k0 += 64) {
    __syncthreads();
#pragma unroll
    for (int i = 0; i < 2; ++i) {
      const int row = (tid >> 3) + i * 32;
      const int col = (tid & 7) * 8;
      *(uint4*)(&As[row * 64 + col]) =
          *(const uint4*)(&A[(size_t)(m0 + row) * K + k0 + col]);
      *(uint4*)(&Bs[row * 64 + col]) =
          *(const uint4*)(&Bm[(size_t)(n0 + row) * K + k0 + col]);
    }
    __syncthreads();
#pragma unroll
    for (int kk = 0; kk < 64; kk += 32) {
      bf16x8 a[2], b[2];
      a[0] = *(const bf16x8*)(&As[(wm * 32 + l16) * 64 + kk + quad * 8]);
      a[1] = *(const bf16x8*)(&As[(wm * 32 + 16 + l16) * 64 + kk + quad * 8]);
      b[0] = *(const bf16x8*)(&Bs[(wn * 32 + l16) * 64 + kk + quad * 8]);
      b[1] = *(const bf16x8*)(&Bs[(wn * 32 + 16 + l16) * 64 + kk + quad * 8]);
#pragma unroll
      for (int i = 0; i < 2; ++i)
#pragma unroll
        for (int j = 0; j < 2; ++j) acc[i][j] = MFMA(a[i], b[j], acc[i][j]);
    }
  }

#pragma unroll
  for (int i = 0; i < 2; ++i) {
#pragma unroll
    for (int j = 0; j < 2; ++j) {
      const int col = n0 + wn * 32 + j * 16 + l16;
      const float bv = bias ? (float)bias[col] : 0.0f;
#pragma unroll
      for (int r = 0; r < 4; ++r) {
        const int row = m0 + wm * 32 + i * 16 + quad * 4 + r;
        C[(size_t)row * N + col] = (OutT)(acc[i][j][r] + bv);
      }
    }
  }
}

// ---------------------------------------------------------------------------
// Windowed attention (MQA), un-normalized softmax: p = exp(min(logit,30)),
// masked -> 0. No running max -> no inf/NaN possible from finite inputs.
// In-place safe: each block exclusively owns its (t-tile, head) q/o slice.
// ---------------------------------------------------------------------------
__global__ __launch_bounds__(256) void attn_win64(
    const bf16* __restrict__ q, const bf16* __restrict__ k,
    const bf16* __restrict__ v, bf16* __restrict__ o) {
  __shared__ __align__(16) bf16 Qs[64 * 64];
  __shared__ __align__(16) bf16 Ks[64 * 64];
  __shared__ __align__(16) bf16 Vt[64 * 64];  // [h][s]
  __shared__ __align__(16) bf16 Ps[64 * 64];

  const int tid  = threadIdx.x;
  const int w    = tid >> 6;
  const int lane = tid & 63;
  const int quad = lane >> 4;
  const int l16  = lane & 15;

  const int t0 = blockIdx.x * 64;
  const int n  = blockIdx.y;
  const int b  = blockIdx.z;
  const float scale = 0.125f;  // 1/sqrt(64)

#pragma unroll
  for (int i = 0; i < 2; ++i) {
    const int row = (tid >> 3) + i * 32;
    const int col = (tid & 7) * 8;
    *(uint4*)(&Qs[row * 64 + col]) =
        *(const uint4*)(&q[((size_t)(b * T_ + t0 + row)) * D_ + n * HD_ + col]);
  }

  f32x4 o_acc[4] = {};
  float l_r[4] = {0.0f, 0.0f, 0.0f, 0.0f};

  for (int st = t0 - WIN_; st <= t0 + WIN_; st += 64) {
    if (st < 0 || st >= T_) continue;  // block-uniform

    __syncthreads();
#pragma unroll
    for (int i = 0; i < 2; ++i) {
      const int row = (tid >> 3) + i * 32;
      const int col = (tid & 7) * 8;
      *(uint4*)(&Ks[row * 64 + col]) =
          *(const uint4*)(&k[((size_t)(b * T_ + st + row)) * HD_ + col]);
      uint4 raw = *(const uint4*)(&v[((size_t)(b * T_ + st + row)) * HD_ + col]);
      const bf16* pr = (const bf16*)&raw;
#pragma unroll
      for (int e = 0; e < 8; ++e) Vt[(col + e) * 64 + row] = pr[e];
    }
    __syncthreads();

    f32x4 sacc[4] = {};
#pragma unroll
    for (int kk = 0; kk < 64; kk += 32) {
      bf16x8 aq = *(const bf16x8*)(&Qs[(w * 16 + l16) * 64 + kk + quad * 8]);
#pragma unroll
      for (int nt = 0; nt < 4; ++nt) {
        bf16x8 bk = *(const bf16x8*)(&Ks[(nt * 16 + l16) * 64 + kk + quad * 8]);
        sacc[nt] = MFMA(aq, bk, sacc[nt]);
      }
    }

#pragma unroll
    for (int r = 0; r < 4; ++r) {
      const int t = t0 + w * 16 + quad * 4 + r;
#pragma unroll
      for (int nt = 0; nt < 4; ++nt) {
        const int s = st + nt * 16 + l16;
        const int d = t - s;
        float sv = fminf(sacc[nt][r] * scale, 30.0f);
        float p = (d > WIN_ || d < -WIN_) ? 0.0f : __expf(sv);
        l_r[r] += p;
        Ps[(w * 16 + quad * 4 + r) * 64 + nt * 16 + l16] = (bf16)p;
      }
    }
    __syncthreads();

#pragma unroll
    for (int kk = 0; kk < 64; kk += 32) {
      bf16x8 ap = *(const bf16x8*)(&Ps[(w * 16 + l16) * 64 + kk + quad * 8]);
#pragma unroll
      for (int nt = 0; nt < 4; ++nt) {
        bf16x8 bv = *(const bf16x8*)(&Vt[(nt * 16 + l16) * 64 + kk + quad * 8]);
        o_acc[nt] = MFMA(ap, bv, o_acc[nt]);
      }
    }
  }

#pragma unroll
  for (int r = 0; r < 4; ++r) {
#pragma unroll
    for (int off = 1; off < 16; off <<= 1) l_r[r] += __shfl_xor(l_r[r], off);
  }

#pragma unroll
  for (int nt = 0; nt < 4; ++nt) {
#pragma unroll
    for (int r = 0; r < 4; ++r) {
      const int t = t0 + w * 16 + quad * 4 + r;
      const int h = nt * 16 + l16;
      o[((size_t)(b * T_ + t)) * D_ + n * HD_ + h] =
          (bf16)(o_acc[nt][r] / (l_r[r] + 1e-30f));
    }
  }
}

// ---------------------------------------------------------------------------
extern "C" void kernel_launch(void* const* d_in, const int* in_sizes, int n_in,
                              void* d_out, int out_size, void* d_ws, size_t ws_size,
                              hipStream_t stream) {
  float* out = (float*)d_out;  // reference output dtype is float32
  const int M = B_ * T_;       // 4096

  // ws layout (bf16 elements after a 16B flag slot)
  char* wsb = (char*)d_ws;
  int* flag = (int*)wsb;
  bf16* base = (bf16*)(wsb + 16);
  bf16* xc  = base;                        // M x 1024
  bf16* Wqc = xc  + (size_t)M * D_;        // 1024 x 1024
  bf16* Wkc = Wqc + (size_t)D_ * D_;       // 64 x 1024
  bf16* Wvc = Wkc + (size_t)HD_ * D_;      // 64 x 1024
  bf16* Wfc = Wvc + (size_t)HD_ * D_;      // 1024 x 1024
  bf16* bfc = Wfc + (size_t)D_ * D_;       // 1024
  bf16* qb  = bfc + D_;                    // M x 1024 (attn out in-place)
  bf16* kb  = qb  + (size_t)M * D_;        // M x 64
  bf16* vb  = kb  + (size_t)M * HD_;       // M x 64

  detect_f32<<<1, 64, 0, stream>>>((const unsigned int*)d_in[1], flag);

  const int nx = M * D_, nw = D_ * D_, nk = HD_ * D_, nb = D_;
  dim3 blk(256);
  conv_to_bf16<<<(nx / 4 + 255) / 256, blk, 0, stream>>>(d_in[0], xc,  nx, flag);
  conv_to_bf16<<<(nw / 4 + 255) / 256, blk, 0, stream>>>(d_in[1], Wqc, nw, flag);
  conv_to_bf16<<<(nk / 4 + 255) / 256, blk, 0, stream>>>(d_in[2], Wkc, nk, flag);
  conv_to_bf16<<<(nk / 4 + 255) / 256, blk, 0, stream>>>(d_in[3], Wvc, nk, flag);
  conv_to_bf16<<<(nw / 4 + 255) / 256, blk, 0, stream>>>(d_in[4], Wfc, nw, flag);
  conv_to_bf16<<<(nb / 4 + 255) / 256, blk, 0, stream>>>(d_in[5], bfc, nb, flag);

  gemm_bt64<bf16><<<dim3(M / 64, D_ / 64), blk, 0, stream>>>(xc, Wqc, qb, nullptr, M, D_, D_);
  gemm_bt64<bf16><<<dim3(M / 64, 1), blk, 0, stream>>>(xc, Wkc, kb, nullptr, M, HD_, D_);
  gemm_bt64<bf16><<<dim3(M / 64, 1), blk, 0, stream>>>(xc, Wvc, vb, nullptr, M, HD_, D_);
  attn_win64<<<dim3(T_ / 64, NH_, B_), blk, 0, stream>>>(qb, kb, vb, qb);
  gemm_bt64<float><<<dim3(M / 64, D_ / 64), blk, 0, stream>>>(qb, Wfc, out, bfc, M, D_, D_);
}

// Round 5
// 166.115 us; speedup vs baseline: 1.4439x; 1.4439x over previous
//
#include <hip/hip_runtime.h>

typedef __bf16 bf16;
typedef __bf16 bf16x8 __attribute__((ext_vector_type(8)));
typedef float  f32x4  __attribute__((ext_vector_type(4)));

#define MFMA(a, b, c) __builtin_amdgcn_mfma_f32_16x16x32_bf16((a), (b), (c), 0, 0, 0)

static constexpr int B_   = 2;
static constexpr int T_   = 2048;
static constexpr int D_   = 1024;
static constexpr int NH_  = 16;
static constexpr int HD_  = 64;
static constexpr int WIN_ = 256;
static constexpr int M_   = B_ * T_;          // 4096
static constexpr int NQKV = D_ + 2 * HD_;     // 1152

// async global->LDS, 16B per lane; LDS dst must be the wave-uniform base
// (HW adds lane*16 itself) [m97/m104-verified semantics]
__device__ __forceinline__ void gld_lds16(const bf16* g, bf16* l) {
  __builtin_amdgcn_global_load_lds(
      (const __attribute__((address_space(1))) void*)g,
      (__attribute__((address_space(3))) void*)l, 16, 0, 0);
}

// ---------------------------------------------------------------------------
// Fused fp32->bf16 conversion of all 6 inputs (inputs confirmed fp32, r3/r4).
// Wq/Wk/Wv land contiguously as Wqkv[1152][1024].
// ---------------------------------------------------------------------------
__global__ __launch_bounds__(256) void conv_all(
    const float* __restrict__ x,  const float* __restrict__ wq,
    const float* __restrict__ wk, const float* __restrict__ wv,
    const float* __restrict__ wf, const float* __restrict__ bv,
    bf16* __restrict__ xc, bf16* __restrict__ wqkv,
    bf16* __restrict__ wfc, bf16* __restrict__ bfc) {
  const long i = (long)(blockIdx.x * 256 + threadIdx.x) * 4;
  const float* src; bf16* dst; long off;
  if      (i < 4194304L) { src = x;  dst = xc;              off = 0; }
  else if (i < 5242880L) { src = wq; dst = wqkv;            off = 4194304L; }
  else if (i < 5308416L) { src = wk; dst = wqkv + 1048576L; off = 5242880L; }
  else if (i < 5373952L) { src = wv; dst = wqkv + 1114112L; off = 5308416L; }
  else if (i < 6422528L) { src = wf; dst = wfc;             off = 5373952L; }
  else if (i < 6423552L) { src = bv; dst = bfc;             off = 6422528L; }
  else return;
  const long j = i - off;
  const float4 v = *(const float4*)(src + j);
  bf16 o[4] = {(bf16)v.x, (bf16)v.y, (bf16)v.z, (bf16)v.w};
  *(uint2*)(dst + j) = *(const uint2*)o;
}

// ---------------------------------------------------------------------------
// 128x128-tile GEMM, BK=64, 256 thr = 4 waves, wave = 64x64 quadrant (4x4
// MFMA 16x16x32), global_load_lds(16B) staging  [m93/m97-verified structure].
// C[M,N] = A[M,K] @ B[N,K]^T.
// EPI=1: QKV split epilogue -> qb (cols<1024), kb (1024..1087),
//        vT TRANSPOSED (1088..1151, vT[h][m], vectorized 4-row stores).
// EPI=2: fp32 out + bias.
// ---------------------------------------------------------------------------
template <int EPI>
__global__ __launch_bounds__(256) void gemm128(
    const bf16* __restrict__ A, const bf16* __restrict__ Bw,
    void* __restrict__ Cout, const bf16* __restrict__ bias,
    bf16* __restrict__ kb, bf16* __restrict__ vT, int N, int K) {
  __shared__ __align__(16) bf16 As[128 * 64];
  __shared__ __align__(16) bf16 Bs[128 * 64];

  const int tid  = threadIdx.x;
  const int w    = tid >> 6;
  const int lane = tid & 63;
  const int quad = lane >> 4;
  const int l16  = lane & 15;
  const int wm   = w & 1;
  const int wn   = w >> 1;
  const int m0   = blockIdx.x * 128;
  const int n0   = blockIdx.y * 128;
  const int lrow = lane >> 3;        // 0..7
  const int lcol = (lane & 7) * 8;   // 0..56

  f32x4 acc[4][4] = {};

  for (int k0 = 0; k0 < K; k0 += 64) {
    __syncthreads();
#pragma unroll
    for (int t = 0; t < 4; ++t) {
      const int inst = w * 4 + t;  // wave-uniform; stages rows inst*8..inst*8+7
      gld_lds16(&A[(size_t)(m0 + inst * 8 + lrow) * K + k0 + lcol],
                &As[inst * 512]);
      gld_lds16(&Bw[(size_t)(n0 + inst * 8 + lrow) * K + k0 + lcol],
                &Bs[inst * 512]);
    }
    __syncthreads();
#pragma unroll
    for (int kk = 0; kk < 64; kk += 32) {
      bf16x8 a[4], b[4];
#pragma unroll
      for (int i = 0; i < 4; ++i)
        a[i] = *(const bf16x8*)&As[(wm * 64 + i * 16 + l16) * 64 + kk + quad * 8];
#pragma unroll
      for (int j = 0; j < 4; ++j)
        b[j] = *(const bf16x8*)&Bs[(wn * 64 + j * 16 + l16) * 64 + kk + quad * 8];
#pragma unroll
      for (int i = 0; i < 4; ++i)
#pragma unroll
        for (int j = 0; j < 4; ++j) acc[i][j] = MFMA(a[i], b[j], acc[i][j]);
    }
  }

  // epilogue: C/D layout col=l16, row=quad*4+r (m89-verified)
#pragma unroll
  for (int i = 0; i < 4; ++i) {
#pragma unroll
    for (int j = 0; j < 4; ++j) {
      const int col     = n0 + wn * 64 + j * 16 + l16;
      const int rowbase = m0 + wm * 64 + i * 16 + quad * 4;
      if (EPI == 1) {
        if (col < D_) {
          bf16* qb = (bf16*)Cout;
#pragma unroll
          for (int r = 0; r < 4; ++r)
            qb[(size_t)(rowbase + r) * D_ + col] = (bf16)acc[i][j][r];
        } else if (col < D_ + HD_) {
#pragma unroll
          for (int r = 0; r < 4; ++r)
            kb[(size_t)(rowbase + r) * HD_ + (col - D_)] = (bf16)acc[i][j][r];
        } else {
          bf16 o[4] = {(bf16)acc[i][j][0], (bf16)acc[i][j][1],
                       (bf16)acc[i][j][2], (bf16)acc[i][j][3]};
          *(uint2*)&vT[(size_t)(col - D_ - HD_) * M_ + rowbase] = *(const uint2*)o;
        }
      } else {
        float* outp = (float*)Cout;
        const float bvv = (float)bias[col];
#pragma unroll
        for (int r = 0; r < 4; ++r)
          outp[(size_t)(rowbase + r) * D_ + col] = acc[i][j][r] + bvv;
      }
    }
  }
}

// ---------------------------------------------------------------------------
// Windowed attention (MQA). V arrives PRE-TRANSPOSED (vT[h][m]) so the PV
// B-operand stages with vectorized b128 writes - no LDS transpose, killing
// the 16-way-conflict scalar writes (r4: 1.7e7 SQ_LDS_BANK_CONFLICT).
// Un-normalized softmax (exp(min(logit,30)), masked->0): NaN-free.
// Ps stride 72 (16B-aligned reads, scalar writes 8-way -> ~4-way).
// In-place safe: block exclusively owns its (t-tile, head) q/o slice.
// ---------------------------------------------------------------------------
__global__ __launch_bounds__(256) void attn_win64(
    const bf16* __restrict__ q, const bf16* __restrict__ k,
    const bf16* __restrict__ vT, bf16* __restrict__ o) {
  __shared__ __align__(16) bf16 Qs[64 * 64];
  __shared__ __align__(16) bf16 Ks[64 * 64];
  __shared__ __align__(16) bf16 Vt[64 * 64];   // [h][s]
  __shared__ __align__(16) bf16 Ps[64 * 72];   // padded stride

  const int tid  = threadIdx.x;
  const int w    = tid >> 6;
  const int lane = tid & 63;
  const int quad = lane >> 4;
  const int l16  = lane & 15;

  const int t0 = blockIdx.x * 64;
  const int n  = blockIdx.y;
  const int b  = blockIdx.z;
  const float scale = 0.125f;  // 1/sqrt(64)

#pragma unroll
  for (int i = 0; i < 2; ++i) {
    const int row = (tid >> 3) + i * 32;
    const int col = (tid & 7) * 8;
    *(uint4*)(&Qs[row * 64 + col]) =
        *(const uint4*)(&q[((size_t)(b * T_ + t0 + row)) * D_ + n * HD_ + col]);
  }

  f32x4 o_acc[4] = {};
  float l_r[4] = {0.0f, 0.0f, 0.0f, 0.0f};

  for (int st = t0 - WIN_; st <= t0 + WIN_; st += 64) {
    if (st < 0 || st >= T_) continue;  // block-uniform

    __syncthreads();
#pragma unroll
    for (int i = 0; i < 2; ++i) {
      const int row = (tid >> 3) + i * 32;
      const int col = (tid & 7) * 8;
      *(uint4*)(&Ks[row * 64 + col]) =
          *(const uint4*)(&k[((size_t)(b * T_ + st + row)) * HD_ + col]);
      *(uint4*)(&Vt[row * 64 + col]) =
          *(const uint4*)(&vT[(size_t)row * M_ + b * T_ + st + col]);
    }
    __syncthreads();

    f32x4 sacc[4] = {};
#pragma unroll
    for (int kk = 0; kk < 64; kk += 32) {
      bf16x8 aq = *(const bf16x8*)(&Qs[(w * 16 + l16) * 64 + kk + quad * 8]);
#pragma unroll
      for (int nt = 0; nt < 4; ++nt) {
        bf16x8 bk = *(const bf16x8*)(&Ks[(nt * 16 + l16) * 64 + kk + quad * 8]);
        sacc[nt] = MFMA(aq, bk, sacc[nt]);
      }
    }

#pragma unroll
    for (int r = 0; r < 4; ++r) {
      const int t = t0 + w * 16 + quad * 4 + r;
#pragma unroll
      for (int nt = 0; nt < 4; ++nt) {
        const int s = st + nt * 16 + l16;
        const int d = t - s;
        float sv = fminf(sacc[nt][r] * scale, 30.0f);
        float p = (d > WIN_ || d < -WIN_) ? 0.0f : __expf(sv);
        l_r[r] += p;
        Ps[(w * 16 + quad * 4 + r) * 72 + nt * 16 + l16] = (bf16)p;
      }
    }
    __syncthreads();

#pragma unroll
    for (int kk = 0; kk < 64; kk += 32) {
      bf16x8 ap = *(const bf16x8*)(&Ps[(w * 16 + l16) * 72 + kk + quad * 8]);
#pragma unroll
      for (int nt = 0; nt < 4; ++nt) {
        bf16x8 bv = *(const bf16x8*)(&Vt[(nt * 16 + l16) * 64 + kk + quad * 8]);
        o_acc[nt] = MFMA(ap, bv, o_acc[nt]);
      }
    }
  }

#pragma unroll
  for (int r = 0; r < 4; ++r) {
#pragma unroll
    for (int off = 1; off < 16; off <<= 1) l_r[r] += __shfl_xor(l_r[r], off);
  }

#pragma unroll
  for (int nt = 0; nt < 4; ++nt) {
#pragma unroll
    for (int r = 0; r < 4; ++r) {
      const int t = t0 + w * 16 + quad * 4 + r;
      const int h = nt * 16 + l16;
      o[((size_t)(b * T_ + t)) * D_ + n * HD_ + h] =
          (bf16)(o_acc[nt][r] / (l_r[r] + 1e-30f));
    }
  }
}

// ---------------------------------------------------------------------------
extern "C" void kernel_launch(void* const* d_in, const int* in_sizes, int n_in,
                              void* d_out, int out_size, void* d_ws, size_t ws_size,
                              hipStream_t stream) {
  float* out = (float*)d_out;  // reference output dtype is float32

  bf16* xc   = (bf16*)d_ws;                   // 4096 x 1024
  bf16* wqkv = xc   + (size_t)M_ * D_;        // 1152 x 1024
  bf16* wfc  = wqkv + (size_t)NQKV * D_;      // 1024 x 1024
  bf16* bfc  = wfc  + (size_t)D_ * D_;        // 1024
  bf16* qb   = bfc  + D_;                     // 4096 x 1024 (attn out in-place)
  bf16* kb   = qb   + (size_t)M_ * D_;        // 4096 x 64
  bf16* vT   = kb   + (size_t)M_ * HD_;       // 64 x 4096 (transposed)

  dim3 blk(256);
  conv_all<<<dim3((6423552 / 4 + 255) / 256), blk, 0, stream>>>(
      (const float*)d_in[0], (const float*)d_in[1], (const float*)d_in[2],
      (const float*)d_in[3], (const float*)d_in[4], (const float*)d_in[5],
      xc, wqkv, wfc, bfc);

  gemm128<1><<<dim3(M_ / 128, NQKV / 128), blk, 0, stream>>>(
      xc, wqkv, (void*)qb, nullptr, kb, vT, NQKV, D_);

  attn_win64<<<dim3(T_ / 64, NH_, B_), blk, 0, stream>>>(qb, kb, vT, qb);

  gemm128<2><<<dim3(M_ / 128, D_ / 128), blk, 0, stream>>>(
      qb, wfc, (void*)out, bfc, nullptr, nullptr, D_, D_);
}

// Round 6
// 159.506 us; speedup vs baseline: 1.5037x; 1.0414x over previous
//
#include <hip/hip_runtime.h>

typedef __bf16 bf16;
typedef __bf16 bf16x8 __attribute__((ext_vector_type(8)));
typedef float  f32x4  __attribute__((ext_vector_type(4)));

#define MFMA(a, b, c) __builtin_amdgcn_mfma_f32_16x16x32_bf16((a), (b), (c), 0, 0, 0)

static constexpr int B_   = 2;
static constexpr int T_   = 2048;
static constexpr int D_   = 1024;
static constexpr int NH_  = 16;
static constexpr int HD_  = 64;
static constexpr int WIN_ = 256;
static constexpr int M_   = B_ * T_;          // 4096
static constexpr int NQKV = D_ + 2 * HD_;     // 1152

// async global->LDS, 16B per lane; global addr per-lane, LDS dst wave-uniform
// base + lane*16 [m97/m104-verified]
__device__ __forceinline__ void gld_lds16(const bf16* g, bf16* l) {
  __builtin_amdgcn_global_load_lds(
      (const __attribute__((address_space(1))) void*)g,
      (__attribute__((address_space(3))) void*)l, 16, 0, 0);
}

// ---------------------------------------------------------------------------
// Fused fp32->bf16 conversion of all 6 inputs. Wq/Wk/Wv -> Wqkv[1152][1024].
// ---------------------------------------------------------------------------
__global__ __launch_bounds__(256) void conv_all(
    const float* __restrict__ x,  const float* __restrict__ wq,
    const float* __restrict__ wk, const float* __restrict__ wv,
    const float* __restrict__ wf, const float* __restrict__ bv,
    bf16* __restrict__ xc, bf16* __restrict__ wqkv,
    bf16* __restrict__ wfc, bf16* __restrict__ bfc) {
  const long i = (long)(blockIdx.x * 256 + threadIdx.x) * 4;
  const float* src; bf16* dst; long off;
  if      (i < 4194304L) { src = x;  dst = xc;              off = 0; }
  else if (i < 5242880L) { src = wq; dst = wqkv;            off = 4194304L; }
  else if (i < 5308416L) { src = wk; dst = wqkv + 1048576L; off = 5242880L; }
  else if (i < 5373952L) { src = wv; dst = wqkv + 1114112L; off = 5308416L; }
  else if (i < 6422528L) { src = wf; dst = wfc;             off = 5373952L; }
  else if (i < 6423552L) { src = bv; dst = bfc;             off = 6422528L; }
  else return;
  const long j = i - off;
  const float4 v = *(const float4*)(src + j);
  bf16 o[4] = {(bf16)v.x, (bf16)v.y, (bf16)v.z, (bf16)v.w};
  *(uint2*)(dst + j) = *(const uint2*)o;
}

// ---------------------------------------------------------------------------
// GEMM, tile M=64 x N=128, BK=64, 256 thr = 4 waves; wave = 32x64 (2x4 MFMA).
// Grid 64 x N/128 -> 576/512 blocks (2.25/CU) vs 128^2's 288 (1.1/CU): the
// r5 grids were grid-size-occupancy-cliffed (m102: 256-block regime = 320 TF).
// C[M,N] = A[M,K] @ B[N,K]^T.  EPI=1: QKV split (q / k / vT transposed).
// EPI=2: fp32 out + bias.
// ---------------------------------------------------------------------------
template <int EPI>
__global__ __launch_bounds__(256) void gemm64x128(
    const bf16* __restrict__ A, const bf16* __restrict__ Bw,
    void* __restrict__ Cout, const bf16* __restrict__ bias,
    bf16* __restrict__ kb, bf16* __restrict__ vT, int N, int K) {
  __shared__ __align__(16) bf16 As[64 * 64];    //  8 KB
  __shared__ __align__(16) bf16 Bs[128 * 64];   // 16 KB

  const int tid  = threadIdx.x;
  const int w    = tid >> 6;
  const int lane = tid & 63;
  const int quad = lane >> 4;
  const int l16  = lane & 15;
  const int wm   = w & 1;   // row half (32 rows)
  const int wn   = w >> 1;  // col half (64 cols)
  const int m0   = blockIdx.x * 64;
  const int n0   = blockIdx.y * 128;
  const int lrow = lane >> 3;        // 0..7
  const int lcol = (lane & 7) * 8;   // 0..56

  f32x4 acc[2][4] = {};

  for (int k0 = 0; k0 < K; k0 += 64) {
    __syncthreads();
    // 24 gld_lds16 insts per block: 8 for As (64 rows), 16 for Bs (128 rows)
#pragma unroll
    for (int t = 0; t < 6; ++t) {
      const int inst = w * 6 + t;  // wave-uniform
      if (inst < 8) {
        gld_lds16(&A[(size_t)(m0 + inst * 8 + lrow) * K + k0 + lcol],
                  &As[inst * 512]);
      } else {
        const int bi = inst - 8;
        gld_lds16(&Bw[(size_t)(n0 + bi * 8 + lrow) * K + k0 + lcol],
                  &Bs[bi * 512]);
      }
    }
    __syncthreads();
#pragma unroll
    for (int kk = 0; kk < 64; kk += 32) {
      bf16x8 a[2], b[4];
#pragma unroll
      for (int i = 0; i < 2; ++i)
        a[i] = *(const bf16x8*)&As[(wm * 32 + i * 16 + l16) * 64 + kk + quad * 8];
#pragma unroll
      for (int j = 0; j < 4; ++j)
        b[j] = *(const bf16x8*)&Bs[(wn * 64 + j * 16 + l16) * 64 + kk + quad * 8];
#pragma unroll
      for (int i = 0; i < 2; ++i)
#pragma unroll
        for (int j = 0; j < 4; ++j) acc[i][j] = MFMA(a[i], b[j], acc[i][j]);
    }
  }

  // epilogue: C/D layout col=l16, row=quad*4+r (m89-verified)
#pragma unroll
  for (int i = 0; i < 2; ++i) {
#pragma unroll
    for (int j = 0; j < 4; ++j) {
      const int col     = n0 + wn * 64 + j * 16 + l16;
      const int rowbase = m0 + wm * 32 + i * 16 + quad * 4;
      if (EPI == 1) {
        if (col < D_) {
          bf16* qb = (bf16*)Cout;
#pragma unroll
          for (int r = 0; r < 4; ++r)
            qb[(size_t)(rowbase + r) * D_ + col] = (bf16)acc[i][j][r];
        } else if (col < D_ + HD_) {
#pragma unroll
          for (int r = 0; r < 4; ++r)
            kb[(size_t)(rowbase + r) * HD_ + (col - D_)] = (bf16)acc[i][j][r];
        } else {
          bf16 o[4] = {(bf16)acc[i][j][0], (bf16)acc[i][j][1],
                       (bf16)acc[i][j][2], (bf16)acc[i][j][3]};
          *(uint2*)&vT[(size_t)(col - D_ - HD_) * M_ + rowbase] = *(const uint2*)o;
        }
      } else {
        float* outp = (float*)Cout;
        const float bvv = (float)bias[col];
#pragma unroll
        for (int r = 0; r < 4; ++r)
          outp[(size_t)(rowbase + r) * D_ + col] = acc[i][j][r] + bvv;
      }
    }
  }
}

// ---------------------------------------------------------------------------
// Windowed attention (MQA), Q-tile = 128 queries: 10 s-tiles/block instead of
// 2x9 for two 64-tiles -> ~1.8x less K/V staging + fewer barrier iterations,
// 2x MFMA per iteration. All staging via global_load_lds(16B).
// V pre-transposed (vT[h][m]); un-normalized softmax (NaN-free); Ps stride 72.
// In-place safe: block exclusively owns its (t-tile, head) q/o slice.
// ---------------------------------------------------------------------------
__global__ __launch_bounds__(256) void attn_win128(
    const bf16* __restrict__ q, const bf16* __restrict__ k,
    const bf16* __restrict__ vT, bf16* __restrict__ o) {
  __shared__ __align__(16) bf16 Qs[128 * 64];   // 16 KB
  __shared__ __align__(16) bf16 Ks[64 * 64];    //  8 KB
  __shared__ __align__(16) bf16 Vt[64 * 64];    //  8 KB [h][s]
  __shared__ __align__(16) bf16 Ps[128 * 72];   // 18 KB padded

  const int tid  = threadIdx.x;
  const int w    = tid >> 6;
  const int lane = tid & 63;
  const int quad = lane >> 4;
  const int l16  = lane & 15;
  const int lrow = lane >> 3;        // 0..7
  const int lcol = (lane & 7) * 8;   // 0..56

  const int t0 = blockIdx.x * 128;
  const int n  = blockIdx.y;
  const int b  = blockIdx.z;
  const float scale = 0.125f;  // 1/sqrt(64)

  // stage Q tile (128 rows x 64): 16 insts, 4 per wave
#pragma unroll
  for (int t = 0; t < 4; ++t) {
    const int inst = w * 4 + t;
    gld_lds16(&q[((size_t)(b * T_ + t0 + inst * 8 + lrow)) * D_ + n * HD_ + lcol],
              &Qs[inst * 512]);
  }

  f32x4 o_acc[2][4] = {};
  float l_r[2][4] = {};

  for (int st = t0 - WIN_; st <= t0 + WIN_ + 64; st += 64) {
    if (st < 0 || st >= T_) continue;  // aligned tiles, block-uniform

    __syncthreads();  // prior iteration's LDS reads complete
    // K: 8 insts (2/wave); V: 8 insts (2/wave)
#pragma unroll
    for (int t = 0; t < 2; ++t) {
      const int inst = w * 2 + t;
      gld_lds16(&k[((size_t)(b * T_ + st + inst * 8 + lrow)) * HD_ + lcol],
                &Ks[inst * 512]);
      gld_lds16(&vT[(size_t)(inst * 8 + lrow) * M_ + b * T_ + st + lcol],
                &Vt[inst * 512]);
    }
    __syncthreads();

    // S = Q K^T : wave w's 32 rows (2 row-groups of 16) x 64 cols
    f32x4 sacc[2][4] = {};
#pragma unroll
    for (int kk = 0; kk < 64; kk += 32) {
      bf16x8 aq[2];
#pragma unroll
      for (int rg = 0; rg < 2; ++rg)
        aq[rg] = *(const bf16x8*)&Qs[(w * 32 + rg * 16 + l16) * 64 + kk + quad * 8];
#pragma unroll
      for (int nt = 0; nt < 4; ++nt) {
        bf16x8 bk = *(const bf16x8*)&Ks[(nt * 16 + l16) * 64 + kk + quad * 8];
#pragma unroll
        for (int rg = 0; rg < 2; ++rg) sacc[rg][nt] = MFMA(aq[rg], bk, sacc[rg][nt]);
      }
    }

    // p = exp(min(logit,30)) (masked -> 0); per-lane row partials
#pragma unroll
    for (int rg = 0; rg < 2; ++rg) {
#pragma unroll
      for (int r = 0; r < 4; ++r) {
        const int t = t0 + w * 32 + rg * 16 + quad * 4 + r;
#pragma unroll
        for (int nt = 0; nt < 4; ++nt) {
          const int s = st + nt * 16 + l16;
          const int d = t - s;
          float sv = fminf(sacc[rg][nt][r] * scale, 30.0f);
          float p = (d > WIN_ || d < -WIN_) ? 0.0f : __expf(sv);
          l_r[rg][r] += p;
          Ps[(w * 32 + rg * 16 + quad * 4 + r) * 72 + nt * 16 + l16] = (bf16)p;
        }
      }
    }
    __syncthreads();

    // O += P V
#pragma unroll
    for (int kk = 0; kk < 64; kk += 32) {
      bf16x8 ap[2];
#pragma unroll
      for (int rg = 0; rg < 2; ++rg)
        ap[rg] = *(const bf16x8*)&Ps[(w * 32 + rg * 16 + l16) * 72 + kk + quad * 8];
#pragma unroll
      for (int nt = 0; nt < 4; ++nt) {
        bf16x8 bv = *(const bf16x8*)&Vt[(nt * 16 + l16) * 64 + kk + quad * 8];
#pragma unroll
        for (int rg = 0; rg < 2; ++rg)
          o_acc[rg][nt] = MFMA(ap[rg], bv, o_acc[rg][nt]);
      }
    }
  }

#pragma unroll
  for (int rg = 0; rg < 2; ++rg)
#pragma unroll
    for (int r = 0; r < 4; ++r)
#pragma unroll
      for (int off = 1; off < 16; off <<= 1)
        l_r[rg][r] += __shfl_xor(l_r[rg][r], off);

#pragma unroll
  for (int rg = 0; rg < 2; ++rg) {
#pragma unroll
    for (int nt = 0; nt < 4; ++nt) {
#pragma unroll
      for (int r = 0; r < 4; ++r) {
        const int t = t0 + w * 32 + rg * 16 + quad * 4 + r;
        const int h = nt * 16 + l16;
        o[((size_t)(b * T_ + t)) * D_ + n * HD_ + h] =
            (bf16)(o_acc[rg][nt][r] / (l_r[rg][r] + 1e-30f));
      }
    }
  }
}

// ---------------------------------------------------------------------------
extern "C" void kernel_launch(void* const* d_in, const int* in_sizes, int n_in,
                              void* d_out, int out_size, void* d_ws, size_t ws_size,
                              hipStream_t stream) {
  float* out = (float*)d_out;  // reference output dtype is float32

  bf16* xc   = (bf16*)d_ws;                   // 4096 x 1024
  bf16* wqkv = xc   + (size_t)M_ * D_;        // 1152 x 1024
  bf16* wfc  = wqkv + (size_t)NQKV * D_;      // 1024 x 1024
  bf16* bfc  = wfc  + (size_t)D_ * D_;        // 1024
  bf16* qb   = bfc  + D_;                     // 4096 x 1024 (attn out in-place)
  bf16* kb   = qb   + (size_t)M_ * D_;        // 4096 x 64
  bf16* vT   = kb   + (size_t)M_ * HD_;       // 64 x 4096 (transposed)

  dim3 blk(256);
  conv_all<<<dim3((6423552 / 4 + 255) / 256), blk, 0, stream>>>(
      (const float*)d_in[0], (const float*)d_in[1], (const float*)d_in[2],
      (const float*)d_in[3], (const float*)d_in[4], (const float*)d_in[5],
      xc, wqkv, wfc, bfc);

  gemm64x128<1><<<dim3(M_ / 64, NQKV / 128), blk, 0, stream>>>(
      xc, wqkv, (void*)qb, nullptr, kb, vT, NQKV, D_);

  attn_win128<<<dim3(T_ / 128, NH_, B_), blk, 0, stream>>>(qb, kb, vT, qb);

  gemm64x128<2><<<dim3(M_ / 64, D_ / 128), blk, 0, stream>>>(
      qb, wfc, (void*)out, bfc, nullptr, nullptr, D_, D_);
}